// Round 12
// baseline (194.786 us; speedup 1.0000x reference)
//
#include <hip/hip_runtime.h>
#include <hip/hip_bf16.h>
#include <hip/hip_cooperative_groups.h>
#include <math.h>

namespace cg = cooperative_groups;

#define N_NODES 50000
#define N_EDGES 800000
#define IN_DIM 128
#define OUT_DIM 64
#define NEG_SLOPE 0.01f
#define TILE_E 768
#define AGG_NPB 32
#define GRID_F 1563        // ceil(N_NODES / AGG_NPB); also 2 gemm tiles/block

typedef unsigned short u16;
typedef unsigned int   u32;
typedef __attribute__((ext_vector_type(8))) short bf16x8_t;
typedef __attribute__((ext_vector_type(4))) float f32x4_t;

static __device__ __forceinline__ u16 f2bf(float x) {
    __hip_bfloat16 b = __float2bfloat16(x);      // hardware cvt (RNE)
    return __builtin_bit_cast(u16, b);
}
static __device__ __forceinline__ float bflo(u32 w) { return __uint_as_float(w << 16); }
static __device__ __forceinline__ float bfhi(u32 w) { return __uint_as_float(w & 0xffff0000u); }

// ---------- shared device bodies ----------

// One-wave MFMA tile: 16 nodes x 64 dims. lane: row=lane&15, kq=lane>>4.
// wlds: bf16 fc_w, padded row of IN_DIM+8.
static __device__ __forceinline__ void gemm_tile(
    int n0, int lane, const float* __restrict__ h,
    const u16 (*wlds)[IN_DIM + 8], const float* __restrict__ attn_w,
    u16* __restrict__ zb, float* __restrict__ s_src, float* __restrict__ s_dst)
{
    const int row = lane & 15;
    const int kq  = lane >> 4;

    bf16x8_t afr[4];
    const float* hrow = h + (size_t)(n0 + row) * IN_DIM + 8 * kq;
#pragma unroll
    for (int kc = 0; kc < 4; ++kc) {
        const float4 f0 = *(const float4*)(hrow + 32 * kc);
        const float4 f1 = *(const float4*)(hrow + 32 * kc + 4);
        bf16x8_t a;
        a[0] = (short)f2bf(f0.x); a[1] = (short)f2bf(f0.y);
        a[2] = (short)f2bf(f0.z); a[3] = (short)f2bf(f0.w);
        a[4] = (short)f2bf(f1.x); a[5] = (short)f2bf(f1.y);
        a[6] = (short)f2bf(f1.z); a[7] = (short)f2bf(f1.w);
        afr[kc] = a;
    }

    f32x4_t acc[4];
#pragma unroll
    for (int dt = 0; dt < 4; ++dt) {
        f32x4_t c = {0.f, 0.f, 0.f, 0.f};
#pragma unroll
        for (int kc = 0; kc < 4; ++kc) {
            const bf16x8_t bfr =
                *(const bf16x8_t*)&wlds[dt * 16 + row][32 * kc + 8 * kq];
            c = __builtin_amdgcn_mfma_f32_16x16x32_bf16(afr[kc], bfr, c, 0, 0, 0);
        }
        acc[dt] = c;
    }

    // D layout (m89): col = lane&15, row = 4*(lane>>4)+reg
#pragma unroll
    for (int dt = 0; dt < 4; ++dt)
#pragma unroll
        for (int r = 0; r < 4; ++r)
            zb[(size_t)(n0 + 4 * kq + r) * OUT_DIM + dt * 16 + row] = f2bf(acc[dt][r]);

    float a_s[4], a_d[4];
#pragma unroll
    for (int dt = 0; dt < 4; ++dt) {
        a_s[dt] = attn_w[dt * 16 + row];
        a_d[dt] = attn_w[OUT_DIM + dt * 16 + row];
    }
#pragma unroll
    for (int r = 0; r < 4; ++r) {
        float ps = 0.f, pd = 0.f;
#pragma unroll
        for (int dt = 0; dt < 4; ++dt) {
            ps = fmaf(acc[dt][r], a_s[dt], ps);
            pd = fmaf(acc[dt][r], a_d[dt], pd);
        }
#pragma unroll
        for (int mm = 1; mm < 16; mm <<= 1) {
            ps += __shfl_xor(ps, mm);
            pd += __shfl_xor(pd, mm);
        }
        if (row == 0) {
            const int n = n0 + 4 * kq + r;
            s_src[n] = ps;
            s_dst[n] = pd;
        }
    }
}

// row_ptr boundary scatter: quad-unit t covers edges [4t, 4t+4)
static __device__ __forceinline__ void rowptr_quad(
    int t, const int* __restrict__ dst, int* __restrict__ row_ptr)
{
    const int eb = 4 * t;
    const int4 d4 = *(const int4*)(dst + eb);       // coalesced
    int prev = (eb == 0) ? -1 : dst[eb - 1];
    const int dd[4] = {d4.x, d4.y, d4.z, d4.w};
#pragma unroll
    for (int k = 0; k < 4; ++k) {
        const int cur = dd[k];
        for (int n = prev + 1; n <= cur; ++n) row_ptr[n] = eb + k;  // rare
        prev = cur;
    }
    if (eb + 4 == N_EDGES)
        for (int n = prev + 1; n <= N_NODES; ++n) row_ptr[n] = N_EDGES;
}

// R9 aggregate body for one block of AGG_NPB nodes; ep = LDS staging tile.
static __device__ __forceinline__ void aggregate_block(
    int nb, int tid, uint2* ep,
    const int* __restrict__ src, const int* __restrict__ dst,
    const int* __restrict__ row_ptr,
    const u16* __restrict__ zb, const float* __restrict__ s_src,
    const float* __restrict__ s_dst, float* __restrict__ out)
{
    const int g   = tid >> 3;        // group = node within block (0..31)
    const int sub = tid & 7;         // dim octet
    const int n   = nb + g;
    const int ntop = (nb + AGG_NPB < N_NODES) ? (nb + AGG_NPB) : N_NODES;

    const int E0 = row_ptr[nb];
    const int E1 = row_ptr[ntop];
    const bool act = n < N_NODES;
    const int e0 = act ? row_ptr[n] : E1;
    const int e1 = act ? row_ptr[n + 1] : E1;

    float denom = 0.f;
    float a0 = 0.f, a1 = 0.f, a2 = 0.f, a3 = 0.f;
    float a4 = 0.f, a5 = 0.f, a6 = 0.f, a7 = 0.f;

    for (int t0 = E0; t0 < E1; t0 += TILE_E) {
        const int tend = (t0 + TILE_E < E1) ? (t0 + TILE_E) : E1;

        __syncthreads();                          // ep safe to overwrite
        for (int idx = t0 + tid; idx < tend; idx += 256) {
            const int se = src[idx];              // coalesced
            const int de = dst[idx];              // coalesced (sorted -> L1)
            float tt = s_src[se] + s_dst[de];
            tt = (tt > 0.f) ? tt : tt * NEG_SLOPE;
            ep[idx - t0] = make_uint2((u32)se, __float_as_uint(__expf(tt)));
        }
        __syncthreads();

        const int l0 = ((e0 > t0) ? e0 : t0) - t0;
        const int l1 = ((e1 < tend) ? e1 : tend) - t0;
#pragma unroll 4
        for (int j = l0; j < l1; ++j) {
            const uint2 sp = ep[j];               // broadcast ds_read_b64
            const float pj = __uint_as_float(sp.y);
            const uint4 w = *(const uint4*)(zb + (size_t)sp.x * OUT_DIM + 8 * sub);
            denom += pj;
            a0 = fmaf(pj, bflo(w.x), a0);  a1 = fmaf(pj, bfhi(w.x), a1);
            a2 = fmaf(pj, bflo(w.y), a2);  a3 = fmaf(pj, bfhi(w.y), a3);
            a4 = fmaf(pj, bflo(w.z), a4);  a5 = fmaf(pj, bfhi(w.z), a5);
            a6 = fmaf(pj, bflo(w.w), a6);  a7 = fmaf(pj, bfhi(w.w), a7);
        }
    }

    if (act) {
        const float inv = (denom > 0.f) ? (1.f / denom) : 0.f;
        float* op = out + (size_t)n * OUT_DIM + 8 * sub;
        *(float4*)(op)     = make_float4(a0 * inv, a1 * inv, a2 * inv, a3 * inv);
        *(float4*)(op + 4) = make_float4(a4 * inv, a5 * inv, a6 * inv, a7 * inv);
    }
}

// ---------- fused cooperative kernel ----------
// Phase 1: stage fc_w->bf16 in LDS; waves 0-1 do one MFMA tile each
// (2 tiles/block x 1563 = 3126 >= 3125; same active-wave/CU density as the
// 782-block gemm), waves 2-3 do the row_ptr scatter (overlapped, not tail).
// grid.sync(). Phase 2: R9 aggregate, LDS reused as ep tile.
__global__ __launch_bounds__(256, 7) void fused_kernel(
    const float* __restrict__ h, const float* __restrict__ fc_w,
    const float* __restrict__ attn_w, const int* __restrict__ dst,
    const int* __restrict__ src,
    u16* __restrict__ zb, float* __restrict__ s_src, float* __restrict__ s_dst,
    int* __restrict__ row_ptr, float* __restrict__ out)
{
    __shared__ __align__(16) u16 wlds[OUT_DIM][IN_DIM + 8];   // 17.4 KB

    const int tid  = threadIdx.x;
    const int wv   = tid >> 6;
    const int lane = tid & 63;

    for (int idx = tid; idx < OUT_DIM * IN_DIM / 2; idx += 256) {
        const int d  = idx >> 6;
        const int kk = idx & 63;
        const float2 f = ((const float2*)fc_w)[idx];
        *(u32*)&wlds[d][2 * kk] = ((u32)f2bf(f.y) << 16) | (u32)f2bf(f.x);
    }
    __syncthreads();

    if (wv < 2) {
        const int wid = blockIdx.x * 2 + wv;
        if (wid < N_NODES / 16)
            gemm_tile(wid * 16, lane, h, wlds, attn_w, zb, s_src, s_dst);
    } else {
        const int t = blockIdx.x * 128 + (tid - 128);
        if (t < N_EDGES / 4)
            rowptr_quad(t, dst, row_ptr);
    }

    cg::this_grid().sync();    // device-scope fence + grid barrier (G16)

    aggregate_block(blockIdx.x * AGG_NPB, tid, (uint2*)&wlds[0][0],
                    src, dst, row_ptr, zb, s_src, s_dst, out);
}

// ---------- fallback two-kernel path (exact R9) ----------
__global__ __launch_bounds__(256) void gemm_fused_kernel(
    const float* __restrict__ h, const float* __restrict__ fc_w,
    const float* __restrict__ attn_w, const int* __restrict__ dst,
    u16* __restrict__ zb, float* __restrict__ s_src, float* __restrict__ s_dst,
    int* __restrict__ row_ptr)
{
    __shared__ __align__(16) u16 wlds[OUT_DIM][IN_DIM + 8];

    const int tid  = threadIdx.x;
    const int lane = tid & 63;
    const int wid  = blockIdx.x * 4 + (tid >> 6);

    for (int idx = tid; idx < OUT_DIM * IN_DIM / 2; idx += 256) {
        const int d  = idx >> 6;
        const int kk = idx & 63;
        const float2 f = ((const float2*)fc_w)[idx];
        *(u32*)&wlds[d][2 * kk] = ((u32)f2bf(f.y) << 16) | (u32)f2bf(f.x);
    }
    __syncthreads();

    if (wid < N_NODES / 16)
        gemm_tile(wid * 16, lane, h, wlds, attn_w, zb, s_src, s_dst);

    const int t = blockIdx.x * 256 + tid;
    if (t < N_EDGES / 4)
        rowptr_quad(t, dst, row_ptr);
}

__global__ __launch_bounds__(256) void aggregate_kernel(
    const int* __restrict__ src, const int* __restrict__ dst,
    const int* __restrict__ row_ptr,
    const u16* __restrict__ zb, const float* __restrict__ s_src,
    const float* __restrict__ s_dst, float* __restrict__ out)
{
    __shared__ __align__(16) uint2 ep[TILE_E];
    aggregate_block(blockIdx.x * AGG_NPB, threadIdx.x, ep,
                    src, dst, row_ptr, zb, s_src, s_dst, out);
}

extern "C" void kernel_launch(void* const* d_in, const int* in_sizes, int n_in,
                              void* d_out, int out_size, void* d_ws, size_t ws_size,
                              hipStream_t stream)
{
    const float* h      = (const float*)d_in[0];
    const int*   src    = (const int*)  d_in[1];
    const int*   dst    = (const int*)  d_in[2];
    const float* fc_w   = (const float*)d_in[3];
    const float* attn_w = (const float*)d_in[4];
    float*       out    = (float*)d_out;

    char* ws = (char*)d_ws;
    u16* zb = (u16*)ws;                                           // 6.4 MB
    ws += ((size_t)N_NODES * OUT_DIM * sizeof(u16) + 255) & ~(size_t)255;
    float* s_src = (float*)ws;
    ws += ((size_t)N_NODES * sizeof(float) + 255) & ~(size_t)255;
    float* s_dst = (float*)ws;
    ws += ((size_t)N_NODES * sizeof(float) + 255) & ~(size_t)255;
    int* row_ptr = (int*)ws;
    (void)ws_size;

    void* kargs[] = {
        (void*)&h, (void*)&fc_w, (void*)&attn_w, (void*)&dst, (void*)&src,
        (void*)&zb, (void*)&s_src, (void*)&s_dst, (void*)&row_ptr, (void*)&out
    };
    hipError_t err = hipLaunchCooperativeKernel(
        reinterpret_cast<void*>(fused_kernel),
        dim3(GRID_F), dim3(256), kargs, 0, stream);

    if (err != hipSuccess) {
        // deterministic fallback: exact R9 two-kernel path
        const int gemm_blocks = (N_NODES / 16 + 3) / 4;           // 782
        gemm_fused_kernel<<<gemm_blocks, 256, 0, stream>>>(
            h, fc_w, attn_w, dst, zb, s_src, s_dst, row_ptr);
        const int agg_blocks = (N_NODES + AGG_NPB - 1) / AGG_NPB; // 1563
        aggregate_kernel<<<agg_blocks, 256, 0, stream>>>(
            src, dst, row_ptr, zb, s_src, s_dst, out);
    }
}

// Round 13
// 34.067 us; speedup vs baseline: 5.7178x; 5.7178x over previous
//
#include <hip/hip_runtime.h>
#include <hip/hip_bf16.h>
#include <math.h>

#define N_NODES 50000
#define N_EDGES 800000
#define IN_DIM 128
#define OUT_DIM 64
#define NEG_SLOPE 0.01f
#define TILE_E 768
#define AGG_NPB 32

typedef unsigned short u16;
typedef unsigned int   u32;
typedef __attribute__((ext_vector_type(8))) short bf16x8_t;
typedef __attribute__((ext_vector_type(4))) float f32x4_t;

static __device__ __forceinline__ u16 f2bf(float x) {
    __hip_bfloat16 b = __float2bfloat16(x);      // hardware cvt (RNE)
    return __builtin_bit_cast(u16, b);
}
static __device__ __forceinline__ float bflo(u32 w) { return __uint_as_float(w << 16); }
static __device__ __forceinline__ float bfhi(u32 w) { return __uint_as_float(w & 0xffff0000u); }

// Kernel A (R9-verified): MFMA gemm + scores + edge-parallel row_ptr
// boundary scatter, all overlapped in one launch.
__global__ __launch_bounds__(256) void gemm_fused_kernel(
    const float* __restrict__ h, const float* __restrict__ fc_w,
    const float* __restrict__ attn_w, const int* __restrict__ dst,
    u16* __restrict__ zb, float* __restrict__ s_src, float* __restrict__ s_dst,
    int* __restrict__ row_ptr)
{
    __shared__ u16 wlds[OUT_DIM][IN_DIM + 8];   // 64 x 136 u16 = 17.4 KB

    const int tid  = threadIdx.x;
    const int lane = tid & 63;
    const int wid  = blockIdx.x * 4 + (tid >> 6);
    const int row  = lane & 15;
    const int kq   = lane >> 4;

    // stage + convert fc_w (conflict-free)
    for (int idx = tid; idx < OUT_DIM * IN_DIM / 2; idx += 256) {
        const int d  = idx >> 6;
        const int kk = idx & 63;
        const float2 f = ((const float2*)fc_w)[idx];
        const u32 w = ((u32)f2bf(f.y) << 16) | (u32)f2bf(f.x);
        *(u32*)&wlds[d][2 * kk] = w;
    }
    __syncthreads();

    if (wid < N_NODES / 16) {              // 3125 waves exactly
        const int n0 = wid * 16;

        bf16x8_t afr[4];
        const float* hrow = h + (size_t)(n0 + row) * IN_DIM + 8 * kq;
#pragma unroll
        for (int kc = 0; kc < 4; ++kc) {
            const float4 f0 = *(const float4*)(hrow + 32 * kc);
            const float4 f1 = *(const float4*)(hrow + 32 * kc + 4);
            bf16x8_t a;
            a[0] = (short)f2bf(f0.x); a[1] = (short)f2bf(f0.y);
            a[2] = (short)f2bf(f0.z); a[3] = (short)f2bf(f0.w);
            a[4] = (short)f2bf(f1.x); a[5] = (short)f2bf(f1.y);
            a[6] = (short)f2bf(f1.z); a[7] = (short)f2bf(f1.w);
            afr[kc] = a;
        }

        f32x4_t acc[4];
#pragma unroll
        for (int dt = 0; dt < 4; ++dt) {
            f32x4_t c = {0.f, 0.f, 0.f, 0.f};
#pragma unroll
            for (int kc = 0; kc < 4; ++kc) {
                const bf16x8_t bfr =
                    *(const bf16x8_t*)&wlds[dt * 16 + row][32 * kc + 8 * kq];
                c = __builtin_amdgcn_mfma_f32_16x16x32_bf16(afr[kc], bfr, c, 0, 0, 0);
            }
            acc[dt] = c;
        }

        // store z (bf16). D layout (m89): col = lane&15, row = 4*(lane>>4)+reg
#pragma unroll
        for (int dt = 0; dt < 4; ++dt)
#pragma unroll
            for (int r = 0; r < 4; ++r)
                zb[(size_t)(n0 + 4 * kq + r) * OUT_DIM + dt * 16 + row] = f2bf(acc[dt][r]);

        float a_s[4], a_d[4];
#pragma unroll
        for (int dt = 0; dt < 4; ++dt) {
            a_s[dt] = attn_w[dt * 16 + row];
            a_d[dt] = attn_w[OUT_DIM + dt * 16 + row];
        }
#pragma unroll
        for (int r = 0; r < 4; ++r) {
            float ps = 0.f, pd = 0.f;
#pragma unroll
            for (int dt = 0; dt < 4; ++dt) {
                ps = fmaf(acc[dt][r], a_s[dt], ps);
                pd = fmaf(acc[dt][r], a_d[dt], pd);
            }
#pragma unroll
            for (int mm = 1; mm < 16; mm <<= 1) {
                ps += __shfl_xor(ps, mm);
                pd += __shfl_xor(pd, mm);
            }
            if (row == 0) {
                const int n = n0 + 4 * kq + r;
                s_src[n] = ps;
                s_dst[n] = pd;
            }
        }
    }

    // row_ptr boundary build: thread t covers edges [4t, 4t+4)
    const int t = blockIdx.x * 256 + tid;
    if (t < N_EDGES / 4) {
        const int eb = 4 * t;
        const int4 d4 = *(const int4*)(dst + eb);       // coalesced
        int prev = (eb == 0) ? -1 : dst[eb - 1];
        const int dd[4] = {d4.x, d4.y, d4.z, d4.w};
#pragma unroll
        for (int k = 0; k < 4; ++k) {
            const int cur = dd[k];
            for (int n = prev + 1; n <= cur; ++n) row_ptr[n] = eb + k;  // rare
            prev = cur;
        }
        if (eb + 4 == N_EDGES)
            for (int n = prev + 1; n <= N_NODES; ++n) row_ptr[n] = N_EDGES;
    }
}

// Kernel B (R9-verified): 32 nodes/block, 8-lane group per node.
// Phase 1: edge-parallel scoring into LDS {src, p}. Phase 2: per-edge
// ds_read_b64 broadcast + ONE uint4 z-gather (8 edges/wave-instr) + 8
// independent fma chains; no cross-lane reductions anywhere.
__global__ __launch_bounds__(256) void aggregate_kernel(
    const int* __restrict__ src, const int* __restrict__ dst,
    const int* __restrict__ row_ptr,
    const u16* __restrict__ zb, const float* __restrict__ s_src,
    const float* __restrict__ s_dst, float* __restrict__ out)
{
    __shared__ uint2 ep[TILE_E];     // {src, exp(score) bits} : 6 KB

    const int tid = threadIdx.x;
    const int g   = tid >> 3;        // group = node within block (0..31)
    const int sub = tid & 7;         // dim octet (dims 8*sub .. 8*sub+7)
    const int nb  = blockIdx.x * AGG_NPB;
    const int n   = nb + g;
    const int ntop = (nb + AGG_NPB < N_NODES) ? (nb + AGG_NPB) : N_NODES;

    const int E0 = row_ptr[nb];
    const int E1 = row_ptr[ntop];
    const bool act = n < N_NODES;
    const int e0 = act ? row_ptr[n] : E1;
    const int e1 = act ? row_ptr[n + 1] : E1;

    float denom = 0.f;
    float a0 = 0.f, a1 = 0.f, a2 = 0.f, a3 = 0.f;
    float a4 = 0.f, a5 = 0.f, a6 = 0.f, a7 = 0.f;

    for (int t0 = E0; t0 < E1; t0 += TILE_E) {
        const int tend = (t0 + TILE_E < E1) ? (t0 + TILE_E) : E1;

        __syncthreads();                          // ep safe to overwrite
        for (int idx = t0 + tid; idx < tend; idx += 256) {
            const int se = src[idx];              // coalesced
            const int de = dst[idx];              // coalesced (sorted -> L1)
            float tt = s_src[se] + s_dst[de];
            tt = (tt > 0.f) ? tt : tt * NEG_SLOPE;
            ep[idx - t0] = make_uint2((u32)se, __float_as_uint(__expf(tt)));
        }
        __syncthreads();

        const int l0 = ((e0 > t0) ? e0 : t0) - t0;
        const int l1 = ((e1 < tend) ? e1 : tend) - t0;
#pragma unroll 4
        for (int j = l0; j < l1; ++j) {
            const uint2 sp = ep[j];               // broadcast ds_read_b64
            const float pj = __uint_as_float(sp.y);
            const uint4 w = *(const uint4*)(zb + (size_t)sp.x * OUT_DIM + 8 * sub);
            denom += pj;
            a0 = fmaf(pj, bflo(w.x), a0);  a1 = fmaf(pj, bfhi(w.x), a1);
            a2 = fmaf(pj, bflo(w.y), a2);  a3 = fmaf(pj, bfhi(w.y), a3);
            a4 = fmaf(pj, bflo(w.z), a4);  a5 = fmaf(pj, bfhi(w.z), a5);
            a6 = fmaf(pj, bflo(w.w), a6);  a7 = fmaf(pj, bfhi(w.w), a7);
        }
    }

    if (act) {
        const float inv = (denom > 0.f) ? (1.f / denom) : 0.f;
        float* op = out + (size_t)n * OUT_DIM + 8 * sub;
        *(float4*)(op)     = make_float4(a0 * inv, a1 * inv, a2 * inv, a3 * inv);
        *(float4*)(op + 4) = make_float4(a4 * inv, a5 * inv, a6 * inv, a7 * inv);
    }
}

extern "C" void kernel_launch(void* const* d_in, const int* in_sizes, int n_in,
                              void* d_out, int out_size, void* d_ws, size_t ws_size,
                              hipStream_t stream)
{
    const float* h      = (const float*)d_in[0];
    const int*   src    = (const int*)  d_in[1];
    const int*   dst    = (const int*)  d_in[2];
    const float* fc_w   = (const float*)d_in[3];
    const float* attn_w = (const float*)d_in[4];
    float*       out    = (float*)d_out;

    char* ws = (char*)d_ws;
    u16* zb = (u16*)ws;                                           // 6.4 MB
    ws += ((size_t)N_NODES * OUT_DIM * sizeof(u16) + 255) & ~(size_t)255;
    float* s_src = (float*)ws;
    ws += ((size_t)N_NODES * sizeof(float) + 255) & ~(size_t)255;
    float* s_dst = (float*)ws;
    ws += ((size_t)N_NODES * sizeof(float) + 255) & ~(size_t)255;
    int* row_ptr = (int*)ws;
    (void)ws_size;

    const int gemm_blocks = (N_NODES / 16 + 3) / 4;               // 782
    gemm_fused_kernel<<<gemm_blocks, 256, 0, stream>>>(
        h, fc_w, attn_w, dst, zb, s_src, s_dst, row_ptr);
    const int agg_blocks = (N_NODES + AGG_NPB - 1) / AGG_NPB;     // 1563
    aggregate_kernel<<<agg_blocks, 256, 0, stream>>>(
        src, dst, row_ptr, zb, s_src, s_dst, out);
}